// Round 1
// 333.149 us; speedup vs baseline: 1.0056x; 1.0056x over previous
//
#include <hip/hip_runtime.h>

// Problem constants (from reference): B,J,C,H,W = 16,16,64,256,256
#define NB 16
#define NJ 16
#define NC 64
#define NHW (256 * 256)  // 65536 spatial elements per (b,j) heatmap channel

// ---------------------------------------------------------------------------
// Phase 1: per-(b,j) argmax over HW, gather pred[b,:,idx], SSE vs gt[b,j,:],
// write raw SSE to ws[bj]. No atomics, no pre-zeroed memory required.
// Grid: B*J = 256 blocks (1 per CU), 1024 threads (16 waves).
// Argmax: float4 coalesced loads (16B/lane); strict '>' keeps first
// occurrence within a thread; min-index on value ties across lanes/waves
// (matches jnp.argmax first-occurrence semantics).
// ---------------------------------------------------------------------------
__global__ __launch_bounds__(1024) void labelloss_phase1(
    const float* __restrict__ heatmap, const float* __restrict__ pred,
    const float* __restrict__ gt, float* __restrict__ ws) {
  const int bj = blockIdx.x;  // 0..255
  const int b = bj >> 4;
  const int j = bj & 15;
  const float4* __restrict__ p4 =
      (const float4*)(heatmap + (size_t)bj * NHW);  // 16384 float4s
  const int t = threadIdx.x;                        // 0..1023

  float best = -INFINITY;
  int besti = 0;
#pragma unroll
  for (int i = 0; i < 16; ++i) {
    const int k = t + i * 1024;  // float4 index, increasing per thread
    const float4 v = p4[k];
    const int base = 4 * k;
    if (v.x > best) { best = v.x; besti = base; }
    if (v.y > best) { best = v.y; besti = base + 1; }
    if (v.z > best) { best = v.z; besti = base + 2; }
    if (v.w > best) { best = v.w; besti = base + 3; }
  }

  // Wave (64-lane) reduction: max value, min index on ties.
#pragma unroll
  for (int off = 32; off > 0; off >>= 1) {
    const float ov = __shfl_down(best, off);
    const int oi = __shfl_down(besti, off);
    if (ov > best || (ov == best && oi < besti)) {
      best = ov;
      besti = oi;
    }
  }

  __shared__ float sval[16];
  __shared__ int sidx[16];
  __shared__ int final_idx;
  const int wave = t >> 6;
  const int lane = t & 63;
  if (lane == 0) {
    sval[wave] = best;
    sidx[wave] = besti;
  }
  __syncthreads();
  if (t == 0) {
    float bv = sval[0];
    int bi = sidx[0];
#pragma unroll
    for (int w = 1; w < 16; ++w) {
      const float v = sval[w];
      const int i = sidx[w];
      if (v > bv || (v == bv && i < bi)) {
        bv = v;
        bi = i;
      }
    }
    final_idx = bi;
  }
  __syncthreads();

  // Wave 0 only: gather pred[b, c=lane, final_idx], squared diff vs gt,
  // wave-reduce sum, single ws write per block.
  if (t < 64) {
    const int c = t;
    const int id = final_idx;
    const float pv = pred[((size_t)(b * NC + c)) * NHW + id];
    const float gv = gt[(b * NJ + j) * NC + c];
    const float d = pv - gv;
    float acc = d * d;
#pragma unroll
    for (int off = 32; off > 0; off >>= 1) acc += __shfl_down(acc, off);
    if (t == 0) ws[bj] = acc;  // raw SSE over C for this (b,j)
  }
}

// ---------------------------------------------------------------------------
// Phase 2: out[b] = sum_j ws[b*16+j] / (J*C). One block, 256 threads
// (thread t owns ws[t]); 16-lane segmented shuffle reduce; 16 writers.
// Fully overwrites out[] (d_out is poisoned before every launch).
// ---------------------------------------------------------------------------
__global__ __launch_bounds__(256) void labelloss_phase2(
    const float* __restrict__ ws, float* __restrict__ out) {
  const int t = threadIdx.x;  // 0..255 == bj
  float acc = ws[t];
#pragma unroll
  for (int off = 8; off > 0; off >>= 1) acc += __shfl_down(acc, off, 16);
  if ((t & 15) == 0) out[t >> 4] = acc * (1.0f / (float)(NJ * NC));
}

extern "C" void kernel_launch(void* const* d_in, const int* in_sizes, int n_in,
                              void* d_out, int out_size, void* d_ws,
                              size_t ws_size, hipStream_t stream) {
  const float* pred = (const float*)d_in[0];     // [B,C,H,W]
  const float* gt = (const float*)d_in[1];       // [B,J,C]
  const float* heatmap = (const float*)d_in[2];  // [B,J,H,W]
  float* out = (float*)d_out;                    // [B]
  float* ws = (float*)d_ws;                      // >= 256 floats

  labelloss_phase1<<<NB * NJ, 1024, 0, stream>>>(heatmap, pred, gt, ws);
  labelloss_phase2<<<1, 256, 0, stream>>>(ws, out);
}